// Round 1
// baseline (688.349 us; speedup 1.0000x reference)
//
#include <hip/hip_runtime.h>
#include <hip/hip_cooperative_groups.h>
#include <math.h>

namespace cg = cooperative_groups;

// HPool: z[n,c] = sum_hw tanh(x[n,c,hw]) * coeff[c, bin(x[n,c,hw])]
// bins = linspace(global_min, global_max, 33), searchsorted-right, clip [0,31].
//
// R7: single cooperative kernel (1024 blocks x 256 = 4 blocks/CU, all
// co-resident). Phase 1: block b min/maxes its OWN contiguous 256-KiB slice
// (nc in [4b, 4b+4)) -> release-store partial. grid.sync(). Cheap 8-KiB
// partial reduce (replaces R5/R6's 4096x16KiB pmm prologue). Phase 2: block b
// re-reads its OWN 4 slices, most-recent-first -> guaranteed L3 hits (x ==
// L3 size) + the ~4MiB/XCD L2-hot slice tails that R6's reversed-dispatch
// scheme missed (pass-1 co-residency means L3 recency is ordered WITHIN each
// slice, not across addresses -- the reversal was a no-op).
//
// Lessons: R3/R4 scattered LDS atomics dead; R5: coeff gather not the
// bottleneck; R6 profile: harness 1-GiB poison fills (~160us each) sit inside
// the timed region and crowd the top-5 -- fusing to ONE dispatch also makes
// our kernel's counters observable.
//
// Shapes: N=64, C=64, HW=16384, BINS=32. x = 256 MiB fp32.

constexpr int NB   = 1024;   // cooperative grid: 4 blocks/CU on 256 CUs
constexpr int NB1  = 2048;   // fallback pass-1 blocks (non-coop path)
constexpr int BT   = 256;    // threads/block
constexpr int BINS = 32;

__device__ __forceinline__ float wave_min(float v) {
#pragma unroll
    for (int off = 32; off > 0; off >>= 1) v = fminf(v, __shfl_down(v, off, 64));
    return v;
}
__device__ __forceinline__ float wave_max(float v) {
#pragma unroll
    for (int off = 32; off > 0; off >>= 1) v = fmaxf(v, __shfl_down(v, off, 64));
    return v;
}
__device__ __forceinline__ float wave_sum(float v) {
#pragma unroll
    for (int off = 32; off > 0; off >>= 1) v += __shfl_down(v, off, 64);
    return v;
}

// ------------------------- fused cooperative kernel -------------------------
__global__ __launch_bounds__(BT, 4) void hpool_fused(
    const float* __restrict__ x, const float* __restrict__ coeff,
    unsigned long long* __restrict__ pmm, float* __restrict__ out,
    int C, int hw4, int nc_total, int n4)
{
    __shared__ float smin[4], smax[4], s_red[4];
    __shared__ float s_par[2];   // 4*inv_step, 4*(-min*inv_step)
    const int t = threadIdx.x, b = blockIdx.x;
    const int lane = t & 63, wave = t >> 6;
    const float4* x4 = (const float4*)x;

    // ---- phase 1: min/max over this block's OWN contiguous slice ----
    const int per = n4 / NB;              // 16384 float4 = 256 KiB = 4 slices
    const int i0  = b * per + t;
    const int it1 = per / BT;             // 64
    float vmin = INFINITY, vmax = -INFINITY;
#pragma unroll 4
    for (int k = 0; k < it1; ++k) {
        float4 v = x4[i0 + k * BT];
        vmin = fminf(vmin, fminf(fminf(v.x, v.y), fminf(v.z, v.w)));
        vmax = fmaxf(vmax, fmaxf(fmaxf(v.x, v.y), fmaxf(v.z, v.w)));
    }
    for (int r = NB * per + b * BT + t; r < n4; r += NB * BT) {  // shape tail
        float4 v = x4[r];
        vmin = fminf(vmin, fminf(fminf(v.x, v.y), fminf(v.z, v.w)));
        vmax = fmaxf(vmax, fmaxf(fmaxf(v.x, v.y), fmaxf(v.z, v.w)));
    }
    vmin = wave_min(vmin);
    vmax = wave_max(vmax);
    if (lane == 0) { smin[wave] = vmin; smax[wave] = vmax; }
    __syncthreads();
    if (t == 0) {
        float2 mm = make_float2(
            fminf(fminf(smin[0], smin[1]), fminf(smin[2], smin[3])),
            fmaxf(fmaxf(smax[0], smax[1]), fmaxf(smax[2], smax[3])));
        // agent-scope release: visible across XCDs after grid.sync()
        __hip_atomic_store(&pmm[b], __builtin_bit_cast(unsigned long long, mm),
                           __ATOMIC_RELEASE, __HIP_MEMORY_SCOPE_AGENT);
    }
    cg::this_grid().sync();

    // ---- global min/max: every block reduces the 8-KiB partial array ----
    vmin = INFINITY; vmax = -INFINITY;
#pragma unroll
    for (int k = t; k < NB; k += BT) {    // 4 iters
        float2 mm = __builtin_bit_cast(float2,
            __hip_atomic_load(&pmm[k], __ATOMIC_ACQUIRE, __HIP_MEMORY_SCOPE_AGENT));
        vmin = fminf(vmin, mm.x);
        vmax = fmaxf(vmax, mm.y);
    }
    vmin = wave_min(vmin);
    vmax = wave_max(vmax);
    if (lane == 0) { smin[wave] = vmin; smax[wave] = vmax; }
    __syncthreads();
    if (t == 0) {
        float m = fminf(fminf(smin[0], smin[1]), fminf(smin[2], smin[3]));
        float M = fmaxf(fmaxf(smax[0], smax[1]), fmaxf(smax[2], smax[3]));
        float step = (M - m) / (float)BINS;
        float inv  = 1.0f / step;
        s_par[0] = 4.0f * inv;            // byte-space binning: idx4 = 4*idx
        s_par[1] = 4.0f * (-m * inv);
    }
    __syncthreads();
    const float inv4 = s_par[0];
    const float nmi4 = s_par[1];

    // ---- phase 2: this block's OWN slices, most-recent-first ----
    auto do_slice = [&](int nc) {
        const int c = nc % C;
        // lane j holds coeff[c, j&31] (wave-replicated); gather via bpermute
        const float cf = coeff[c * BINS + (lane & (BINS - 1))];
        const float4* base = x4 + (size_t)nc * hw4;
        float acc0 = 0.0f, acc1 = 0.0f;
        const int it2 = hw4 / BT;         // 16
        auto contrib = [&](float v) -> float {
            // byte-space bin: floor(4*sc)&~3 == 4*floor(sc) for sc>=0
            float sc4 = fmaf(v, inv4, nmi4);
            int  idx4 = (int)sc4;
            idx4 = idx4 > 4 * (BINS - 1) ? 4 * (BINS - 1) : (idx4 & ~3);
            float w   = __builtin_bit_cast(float,
                          __builtin_amdgcn_ds_bpermute(idx4, __builtin_bit_cast(int, cf)));
            float e   = __expf(2.0f * v);          // |2v| < ~12, no overflow
            float th  = fmaf(-2.0f, __frcp_rn(e + 1.0f), 1.0f);  // tanh(v)
            return th * w;
        };
#pragma unroll 4
        for (int k = it2 - 1; k >= 0; --k) {       // tail-first: most recent
            float4 v = base[t + BT * k];
            acc0 += contrib(v.x);
            acc1 += contrib(v.y);
            acc0 += contrib(v.z);
            acc1 += contrib(v.w);
        }
        float acc = wave_sum(acc0 + acc1);
        if (lane == 0) s_red[wave] = acc;
        __syncthreads();
        if (t == 0) out[nc] = s_red[0] + s_red[1] + s_red[2] + s_red[3];
        __syncthreads();                  // s_red reuse across slices
    };

    const int spb = nc_total / NB;        // 4 slices/block
    for (int s = spb - 1; s >= 0; --s) do_slice(b * spb + s);
    for (int nc = NB * spb + b; nc < nc_total; nc += NB) do_slice(nc);  // tail
}

// --------------------- fallback path (non-cooperative) ----------------------
__global__ __launch_bounds__(BT) void minmax_partial(
    const float4* __restrict__ x4, int n4, float2* __restrict__ pmm) {
    const int per = n4 / NB1;
    const int i0  = blockIdx.x * per + threadIdx.x;
    const int iters = per / BT;
    float vmin = INFINITY, vmax = -INFINITY;
#pragma unroll 4
    for (int k = 0; k < iters; ++k) {
        float4 v = x4[i0 + k * BT];
        vmin = fminf(vmin, fminf(fminf(v.x, v.y), fminf(v.z, v.w)));
        vmax = fmaxf(vmax, fmaxf(fmaxf(v.x, v.y), fmaxf(v.z, v.w)));
    }
    for (int r = NB1 * per + blockIdx.x * BT + threadIdx.x; r < n4; r += NB1 * BT) {
        float4 v = x4[r];
        vmin = fminf(vmin, fminf(fminf(v.x, v.y), fminf(v.z, v.w)));
        vmax = fmaxf(vmax, fmaxf(fmaxf(v.x, v.y), fmaxf(v.z, v.w)));
    }
    __shared__ float smin[4], smax[4];
    const int lane = threadIdx.x & 63, wave = threadIdx.x >> 6;
    vmin = wave_min(vmin);
    vmax = wave_max(vmax);
    if (lane == 0) { smin[wave] = vmin; smax[wave] = vmax; }
    __syncthreads();
    if (threadIdx.x == 0) {
        pmm[blockIdx.x] = make_float2(
            fminf(fminf(smin[0], smin[1]), fminf(smin[2], smin[3])),
            fmaxf(fmaxf(smax[0], smax[1]), fmaxf(smax[2], smax[3])));
    }
}

__global__ __launch_bounds__(BT) void hpool_main(
    const float* __restrict__ x, const float* __restrict__ coeff,
    const float2* __restrict__ pmm, float* __restrict__ out,
    int C, int hw4, int nc_total) {
    __shared__ float smin[4], smax[4], s_red[4];
    __shared__ float s_par[2];
    const int t    = threadIdx.x;
    const int nc   = nc_total - 1 - blockIdx.x;
    const int c    = nc % C;
    const int lane = t & 63, wave = t >> 6;
    const float cf = coeff[c * BINS + (lane & (BINS - 1))];
    float vmin = INFINITY, vmax = -INFINITY;
#pragma unroll
    for (int k = t; k < NB1; k += BT) {
        float2 mm = pmm[k];
        vmin = fminf(vmin, mm.x);
        vmax = fmaxf(vmax, mm.y);
    }
    vmin = wave_min(vmin);
    vmax = wave_max(vmax);
    if (lane == 0) { smin[wave] = vmin; smax[wave] = vmax; }
    __syncthreads();
    if (t == 0) {
        float m = fminf(fminf(smin[0], smin[1]), fminf(smin[2], smin[3]));
        float M = fmaxf(fmaxf(smax[0], smax[1]), fmaxf(smax[2], smax[3]));
        float step = (M - m) / (float)BINS;
        float inv  = 1.0f / step;
        s_par[0] = 4.0f * inv;
        s_par[1] = 4.0f * (-m * inv);
    }
    __syncthreads();
    const float inv4 = s_par[0];
    const float nmi4 = s_par[1];
    const float4* base = (const float4*)x + (size_t)nc * hw4;
    float acc0 = 0.0f, acc1 = 0.0f;
    const int iters = hw4 / BT;
    auto contrib = [&](float v) -> float {
        float sc4 = fmaf(v, inv4, nmi4);
        int  idx4 = (int)sc4;
        idx4 = idx4 > 4 * (BINS - 1) ? 4 * (BINS - 1) : (idx4 & ~3);
        float w   = __builtin_bit_cast(float,
                      __builtin_amdgcn_ds_bpermute(idx4, __builtin_bit_cast(int, cf)));
        float e   = __expf(2.0f * v);
        float th  = fmaf(-2.0f, __frcp_rn(e + 1.0f), 1.0f);
        return th * w;
    };
#pragma unroll 4
    for (int k = 0; k < iters; ++k) {
        float4 v = base[t + BT * k];
        acc0 += contrib(v.x);
        acc1 += contrib(v.y);
        acc0 += contrib(v.z);
        acc1 += contrib(v.w);
    }
    float acc = wave_sum(acc0 + acc1);
    if (lane == 0) s_red[wave] = acc;
    __syncthreads();
    if (t == 0) out[nc] = s_red[0] + s_red[1] + s_red[2] + s_red[3];
}

extern "C" void kernel_launch(void* const* d_in, const int* in_sizes, int n_in,
                              void* d_out, int out_size, void* d_ws, size_t ws_size,
                              hipStream_t stream) {
    const float* x     = (const float*)d_in[0];
    const float* coeff = (const float*)d_in[1];
    float* out = (float*)d_out;

    const int total = in_sizes[0];             // 67,108,864 elements
    const int n4    = total / 4;
    const int C     = in_sizes[1] / BINS;      // 64
    const int NC    = out_size;                // 4096
    const int hw4   = total / NC / 4;          // 4096 float4 per (n,c)

    unsigned long long* pmm = (unsigned long long*)d_ws;  // NB u64 = 8 KiB
    void* args[] = {(void*)&x, (void*)&coeff, (void*)&pmm, (void*)&out,
                    (void*)&C, (void*)&hw4, (void*)&NC, (void*)&n4};
    hipError_t err = hipLaunchCooperativeKernel((const void*)hpool_fused,
                                                dim3(NB), dim3(BT), args, 0, stream);
    if (err != hipSuccess) {
        (void)hipGetLastError();               // clear, take non-coop path
        float2* pmm2 = (float2*)d_ws;
        minmax_partial<<<NB1, BT, 0, stream>>>((const float4*)x, n4, pmm2);
        hpool_main<<<NC, BT, 0, stream>>>(x, coeff, pmm2, out, C, hw4, NC);
    }
}

// Round 3
// 415.970 us; speedup vs baseline: 1.6548x; 1.6548x over previous
//
#include <hip/hip_runtime.h>
#include <math.h>

// HPool: z[n,c] = sum_hw tanh(x[n,c,hw]) * coeff[c, bin(x[n,c,hw])]
// bins = linspace(global_min, global_max, 33), searchsorted-right, clip [0,31].
//
// R9 == R8 resubmitted (R8's bench died with "container failed twice" --
// infra flake, no profile; kernel audited for OOB/hang risk, none found).
//
// R8: back to two plain dispatches. R7's cooperative fusion proved the memory
// model (FETCH ~= 247 MiB = ONE HBM pass; phase 2 entirely L3-served since
// x == L3 size = 256 MiB, order-independent) but was latency-bound:
// VALUBusy 10%, occupancy capped at 16 waves/CU by launch_bounds(,4) +
// co-residency, and load->use serialization in the inner loop.
// Fixes here:
//   pass1: grid-stride interleave (no aligned-stride channel hotspot),
//          unroll 8, dual min/max accumulators.
//   pass2: one block per (n,c), 512 threads; the whole row is 8 float4/thread
//          -- load ALL 8 into registers first (8 global_load_dwordx4 in
//          flight), then run the 32-element contrib block. No launch-bounds
//          cap: VGPR ~80 still gives >=2-3 blocks/CU = 16-24 waves with 8x
//          the in-flight bytes of R7.
//
// Lessons: R3/R4 scattered LDS atomics dead; R5: coeff gather not the
// bottleneck; R6/R7: pass-2 re-read is L3-hit regardless of order; R7:
// cooperative co-residency caps occupancy -- don't fuse this one.
//
// Shapes: N=64, C=64, HW=16384, BINS=32. x = 256 MiB fp32.

constexpr int NB1  = 2048;   // pass-1 blocks (8/CU)
constexpr int BT1  = 256;    // pass-1 threads/block
constexpr int BT2  = 512;    // pass-2 threads/block (8 waves)
constexpr int BINS = 32;

__device__ __forceinline__ float wave_min(float v) {
#pragma unroll
    for (int off = 32; off > 0; off >>= 1) v = fminf(v, __shfl_down(v, off, 64));
    return v;
}
__device__ __forceinline__ float wave_max(float v) {
#pragma unroll
    for (int off = 32; off > 0; off >>= 1) v = fmaxf(v, __shfl_down(v, off, 64));
    return v;
}
__device__ __forceinline__ float wave_sum(float v) {
#pragma unroll
    for (int off = 32; off > 0; off >>= 1) v += __shfl_down(v, off, 64);
    return v;
}

// ---------------- pass 1: grid-stride min/max partials ----------------
__global__ __launch_bounds__(BT1) void minmax_partial(
    const float4* __restrict__ x4, int n4, float2* __restrict__ pmm) {
    const int tid    = blockIdx.x * BT1 + threadIdx.x;
    const int stride = NB1 * BT1;            // 524,288 float4 = 8 MiB sweep
    const int iters  = n4 / stride;          // 32 for the fixed shapes
    float vmin0 = INFINITY, vmax0 = -INFINITY;
    float vmin1 = INFINITY, vmax1 = -INFINITY;
#pragma unroll 8
    for (int k = 0; k < iters; ++k) {
        float4 v = x4[tid + k * stride];
        vmin0 = fminf(vmin0, fminf(v.x, v.y));
        vmax0 = fmaxf(vmax0, fmaxf(v.x, v.y));
        vmin1 = fminf(vmin1, fminf(v.z, v.w));
        vmax1 = fmaxf(vmax1, fmaxf(v.z, v.w));
    }
    for (int i = tid + iters * stride; i < n4; i += stride) {   // shape tail
        float4 v = x4[i];
        vmin0 = fminf(vmin0, fminf(v.x, v.y));
        vmax0 = fmaxf(vmax0, fmaxf(v.x, v.y));
        vmin1 = fminf(vmin1, fminf(v.z, v.w));
        vmax1 = fmaxf(vmax1, fmaxf(v.z, v.w));
    }
    float vmin = fminf(vmin0, vmin1), vmax = fmaxf(vmax0, vmax1);
    __shared__ float smin[4], smax[4];
    const int lane = threadIdx.x & 63, wave = threadIdx.x >> 6;
    vmin = wave_min(vmin);
    vmax = wave_max(vmax);
    if (lane == 0) { smin[wave] = vmin; smax[wave] = vmax; }
    __syncthreads();
    if (threadIdx.x == 0) {
        pmm[blockIdx.x] = make_float2(
            fminf(fminf(smin[0], smin[1]), fminf(smin[2], smin[3])),
            fmaxf(fmaxf(smax[0], smax[1]), fmaxf(smax[2], smax[3])));
    }
}

// ------------- pass 2: fused pmm-reduce + main kernel, 512 thr -------------
__global__ __launch_bounds__(BT2) void hpool_main(
    const float* __restrict__ x, const float* __restrict__ coeff,
    const float2* __restrict__ pmm, float* __restrict__ out,
    int C, int hw4, int nc_total) {
    __shared__ float smin[8], smax[8], s_red[8];
    __shared__ float s_par[2];                 // 4*inv_step, 4*(-min*inv_step)
    const int t    = threadIdx.x;
    const int nc   = blockIdx.x;
    const int c    = nc % C;
    const int lane = t & 63, wave = t >> 6;

    // per-lane coeff fragment: lane j holds coeff[c, j&31] (wave-replicated)
    const float cf = coeff[c * BINS + (lane & (BINS - 1))];

    // prologue: every block reduces the 2048 partials (L2/L3-hot, 16 KiB)
    float vmin = INFINITY, vmax = -INFINITY;
#pragma unroll
    for (int k = t; k < NB1; k += BT2) {       // 4 iters
        float2 mm = pmm[k];
        vmin = fminf(vmin, mm.x);
        vmax = fmaxf(vmax, mm.y);
    }
    vmin = wave_min(vmin);
    vmax = wave_max(vmax);
    if (lane == 0) { smin[wave] = vmin; smax[wave] = vmax; }
    __syncthreads();
    if (t == 0) {
        float m = fminf(fminf(fminf(smin[0], smin[1]), fminf(smin[2], smin[3])),
                        fminf(fminf(smin[4], smin[5]), fminf(smin[6], smin[7])));
        float M = fmaxf(fmaxf(fmaxf(smax[0], smax[1]), fmaxf(smax[2], smax[3])),
                        fmaxf(fmaxf(smax[4], smax[5]), fmaxf(smax[6], smax[7])));
        float step = (M - m) / (float)BINS;
        float inv  = 1.0f / step;
        s_par[0] = 4.0f * inv;                 // byte-space binning: idx4 = 4*idx
        s_par[1] = 4.0f * (-m * inv);
    }
    __syncthreads();
    const float inv4 = s_par[0];
    const float nmi4 = s_par[1];

    const float4* base = (const float4*)x + (size_t)nc * hw4;
    float acc0 = 0.0f, acc1 = 0.0f;

    auto contrib = [&](float v) -> float {
        // byte-space bin: floor(4*sc)&~3 == 4*floor(sc) for sc>=0; feeds
        // ds_bpermute's byte-addressed lane select without an extra shift.
        float sc4 = fmaf(v, inv4, nmi4);
        int  idx4 = (int)sc4;
        idx4 = idx4 > 4 * (BINS - 1) ? 4 * (BINS - 1) : (idx4 & ~3);
        float w   = __builtin_bit_cast(float,
                      __builtin_amdgcn_ds_bpermute(idx4, __builtin_bit_cast(int, cf)));
        float e   = __expf(2.0f * v);          // |2v| < ~12, no overflow
        float th  = fmaf(-2.0f, __frcp_rn(e + 1.0f), 1.0f);  // tanh(v)
        return th * w;
    };

    if (hw4 == 8 * BT2) {
        // fixed-shape fast path: whole row = 8 float4/thread. Hoist ALL loads
        // -> 8 global_load_dwordx4 in flight per thread before any use.
        float4 buf[8];
#pragma unroll
        for (int k = 0; k < 8; ++k) buf[k] = base[t + BT2 * k];
#pragma unroll
        for (int k = 0; k < 8; ++k) {
            acc0 += contrib(buf[k].x);
            acc1 += contrib(buf[k].y);
            acc0 += contrib(buf[k].z);
            acc1 += contrib(buf[k].w);
        }
    } else {
        // generic path (robust to shape changes)
        for (int i = t; i < hw4; i += BT2) {
            float4 v = base[i];
            acc0 += contrib(v.x);
            acc1 += contrib(v.y);
            acc0 += contrib(v.z);
            acc1 += contrib(v.w);
        }
    }

    float acc = wave_sum(acc0 + acc1);
    if (lane == 0) s_red[wave] = acc;
    __syncthreads();
    if (t == 0) {
        out[nc] = ((s_red[0] + s_red[1]) + (s_red[2] + s_red[3]))
                + ((s_red[4] + s_red[5]) + (s_red[6] + s_red[7]));
    }
}

extern "C" void kernel_launch(void* const* d_in, const int* in_sizes, int n_in,
                              void* d_out, int out_size, void* d_ws, size_t ws_size,
                              hipStream_t stream) {
    const float* x     = (const float*)d_in[0];
    const float* coeff = (const float*)d_in[1];
    float*  out = (float*)d_out;
    float2* pmm = (float2*)d_ws;               // NB1 float2 = 16 KiB

    const int total = in_sizes[0];             // 67,108,864 elements
    const int n4    = total / 4;
    const int C     = in_sizes[1] / BINS;      // 64
    const int NC    = out_size;                // 4096
    const int hw4   = total / NC / 4;          // 4096 float4 per (n,c)

    minmax_partial<<<NB1, BT1, 0, stream>>>((const float4*)x, n4, pmm);
    hpool_main<<<NC, BT2, 0, stream>>>(x, coeff, pmm, out, C, hw4, NC);
}